// Round 1
// baseline (4649.345 us; speedup 1.0000x reference)
//
#include <hip/hip_runtime.h>
#include <hip/hip_bf16.h>

// ---------------------------------------------------------------------------
// LSTM (faithful-bug variant) on MI355X.
// carry (a, b):  a = "h" slot (cell chain), b = "c" slot (hidden chain)
//   z[g] = b_prev @ Wc[g]^T + T[x_t][g]          (T holds embed-part + bias)
//   g=tanh(z0) i=sig(z1) f=sig(z2) o=sig(z3)
//   a_new = g*i + a_prev*f ;  b_new = tanh(a_new)*o
// output = softmax(a_final @ w_p^T + b_p)
// ---------------------------------------------------------------------------

typedef __attribute__((ext_vector_type(8))) short bf16x8;
typedef __attribute__((ext_vector_type(4))) float f32x4;

#define GLOBAL_AS __attribute__((address_space(1)))
#define LDS_AS    __attribute__((address_space(3)))

static __device__ __forceinline__ void async_copy16(const void* g, void* l) {
    __builtin_amdgcn_global_load_lds((const GLOBAL_AS void*)g, (LDS_AS void*)l, 16, 0, 0);
}

// ---------------- prep 1: gate table T[s][col], col = gate*1024 + j --------
__global__ __launch_bounds__(256) void prep_table(
    const float* __restrict__ embed,                       // [128][256]
    const float* __restrict__ wg, const float* __restrict__ wi,
    const float* __restrict__ wf, const float* __restrict__ wo,
    const float* __restrict__ bg, const float* __restrict__ bi,
    const float* __restrict__ bff, const float* __restrict__ bo,
    float* __restrict__ T)                                 // [128][4096]
{
    __shared__ float e[256];
    const int col = blockIdx.x * 256 + threadIdx.x;        // 0..4095
    const int g = col >> 10, j = col & 1023;
    const float* w = (g == 0 ? wg : g == 1 ? wi : g == 2 ? wf : wo) + (size_t)j * 1280;
    const float bias = (g == 0 ? bg : g == 1 ? bi : g == 2 ? bff : bo)[j];
    const float4* w4 = (const float4*)w;
    for (int s = 0; s < 128; ++s) {
        __syncthreads();
        e[threadIdx.x] = embed[s * 256 + threadIdx.x];
        __syncthreads();
        const float4* e4 = (const float4*)e;
        float acc = bias;
        #pragma unroll 8
        for (int d = 0; d < 64; ++d) {
            float4 ev = e4[d], wv = w4[d];
            acc += ev.x * wv.x + ev.y * wv.y + ev.z * wv.z + ev.w * wv.w;
        }
        T[(size_t)s * 4096 + col] = acc;
    }
}

// ---------------- prep 2: pack recurrent weights to bf16 [4096][1024] ------
__global__ __launch_bounds__(256) void pack_w(
    const float* __restrict__ wg, const float* __restrict__ wi,
    const float* __restrict__ wf, const float* __restrict__ wo,
    __hip_bfloat16* __restrict__ Wb)
{
    const int col = blockIdx.x;                            // 0..4095
    const int g = col >> 10, j = col & 1023;
    const float* w = (g == 0 ? wg : g == 1 ? wi : g == 2 ? wf : wo)
                     + (size_t)j * 1280 + 256;             // skip embed part
    __hip_bfloat16* out = Wb + (size_t)col * 1024;
    for (int k = threadIdx.x; k < 1024; k += 256)
        out[k] = __float2bfloat16(w[k]);
}

// ---------------- per-step GEMM: Z = Bh @ Wb^T  (bf16 MFMA) ----------------
// BM=64 BN=128 BK=32, 256 threads (4 waves, 2x2), grid (16, 32) = 512 WGs
__global__ __launch_bounds__(256) void gemm_step(
    const __hip_bfloat16* __restrict__ Bh,   // [1024][1024] bf16
    const __hip_bfloat16* __restrict__ Wb,   // [4096][1024] bf16
    float* __restrict__ Z)                   // [1024][4096] f32
{
    __shared__ __hip_bfloat16 As[64 * 32];
    __shared__ __hip_bfloat16 Bs[128 * 32];
    const int tid = threadIdx.x;
    const int brow = blockIdx.x * 64;
    const int bcol = blockIdx.y * 128;
    const int w = tid >> 6, l = tid & 63;
    const int wm = w >> 1, wn = w & 1;       // wave tile 32x64
    const int lr = tid >> 2;                 // staging row 0..63
    const int lk = (tid & 3) * 8;            // staging k-elem offset

    f32x4 acc[2][4];
    const f32x4 z4 = {0.f, 0.f, 0.f, 0.f};
    #pragma unroll
    for (int mi = 0; mi < 2; ++mi)
        #pragma unroll
        for (int ni = 0; ni < 4; ++ni) acc[mi][ni] = z4;

    for (int k0 = 0; k0 < 1024; k0 += 32) {
        // stage A: 64 rows x 32 k (one 16B/lane issue)
        async_copy16(Bh + (size_t)(brow + lr) * 1024 + k0 + lk, &As[tid * 8]);
        // stage B: 128 rows x 32 k (two issues)
        #pragma unroll
        for (int i = 0; i < 2; ++i)
            async_copy16(Wb + (size_t)(bcol + i * 64 + lr) * 1024 + k0 + lk,
                         &Bs[(i * 256 + tid) * 8]);
        __syncthreads();

        bf16x8 af[2], bfr[4];
        #pragma unroll
        for (int mi = 0; mi < 2; ++mi)
            af[mi] = *(const bf16x8*)&As[(wm * 32 + mi * 16 + (l & 15)) * 32 + (l >> 4) * 8];
        #pragma unroll
        for (int ni = 0; ni < 4; ++ni)
            bfr[ni] = *(const bf16x8*)&Bs[(wn * 64 + ni * 16 + (l & 15)) * 32 + (l >> 4) * 8];
        #pragma unroll
        for (int mi = 0; mi < 2; ++mi)
            #pragma unroll
            for (int ni = 0; ni < 4; ++ni)
                acc[mi][ni] = __builtin_amdgcn_mfma_f32_16x16x32_bf16(
                    af[mi], bfr[ni], acc[mi][ni], 0, 0, 0);
        __syncthreads();
    }

    // C/D layout: col = l&15, row = (l>>4)*4 + reg   [m89/m91 verified]
    #pragma unroll
    for (int mi = 0; mi < 2; ++mi)
        #pragma unroll
        for (int ni = 0; ni < 4; ++ni) {
            const int col = bcol + wn * 64 + ni * 16 + (l & 15);
            const int rbase = brow + wm * 32 + mi * 16 + (l >> 4) * 4;
            #pragma unroll
            for (int r = 0; r < 4; ++r)
                Z[(size_t)(rbase + r) * 4096 + col] = acc[mi][ni][r];
        }
}

// ---------------- gates + state update -------------------------------------
__global__ __launch_bounds__(256) void gates_step(
    const float* __restrict__ Z,             // [1024][4096]
    const float* __restrict__ T,             // [128][4096]
    const int* __restrict__ X,               // [1024][128]
    float* __restrict__ A,                   // [1024][1024] cell state
    __hip_bfloat16* __restrict__ Bh,         // [1024][1024] hidden (bf16)
    int t, int first)
{
    const int row = blockIdx.x;
    const int s = X[row * 128 + t];
    const float* zr = Z + (size_t)row * 4096;
    const float* tr = T + (size_t)s * 4096;
    for (int j = threadIdx.x; j < 1024; j += 256) {
        float z0 = tr[j], z1 = tr[1024 + j], z2 = tr[2048 + j], z3 = tr[3072 + j];
        if (!first) {
            z0 += zr[j]; z1 += zr[1024 + j]; z2 += zr[2048 + j]; z3 += zr[3072 + j];
        }
        const float gg = tanhf(z0);
        const float ii = 1.f / (1.f + __expf(-z1));
        const float ff = 1.f / (1.f + __expf(-z2));
        const float oo = 1.f / (1.f + __expf(-z3));
        const float ap = first ? 0.f : A[(size_t)row * 1024 + j];
        const float na = gg * ii + ap * ff;
        A[(size_t)row * 1024 + j] = na;
        Bh[(size_t)row * 1024 + j] = __float2bfloat16(tanhf(na) * oo);
    }
}

// ---------------- final projection + softmax -------------------------------
__global__ __launch_bounds__(256) void proj_softmax(
    const float* __restrict__ A,             // [1024][1024]
    const float* __restrict__ Wp,            // [10][1024]
    const float* __restrict__ bp,            // [10]
    float* __restrict__ out)                 // [1024][10]
{
    const int row = blockIdx.x;
    const float* a = A + (size_t)row * 1024;
    float p[10];
    #pragma unroll
    for (int c = 0; c < 10; ++c) p[c] = 0.f;
    for (int k = threadIdx.x; k < 1024; k += 256) {
        const float av = a[k];
        #pragma unroll
        for (int c = 0; c < 10; ++c) p[c] += av * Wp[c * 1024 + k];
    }
    #pragma unroll
    for (int c = 0; c < 10; ++c)
        #pragma unroll
        for (int off = 32; off; off >>= 1) p[c] += __shfl_down(p[c], off);
    __shared__ float red[4][10];
    const int wv = threadIdx.x >> 6, ln = threadIdx.x & 63;
    if (ln == 0)
        for (int c = 0; c < 10; ++c) red[wv][c] = p[c];
    __syncthreads();
    if (threadIdx.x == 0) {
        float logits[10], mx = -1e30f;
        for (int c = 0; c < 10; ++c) {
            logits[c] = red[0][c] + red[1][c] + red[2][c] + red[3][c] + bp[c];
            mx = fmaxf(mx, logits[c]);
        }
        float sum = 0.f;
        for (int c = 0; c < 10; ++c) { logits[c] = __expf(logits[c] - mx); sum += logits[c]; }
        const float inv = 1.f / sum;
        for (int c = 0; c < 10; ++c) out[(size_t)row * 10 + c] = logits[c] * inv;
    }
}

// ---------------------------------------------------------------------------
extern "C" void kernel_launch(void* const* d_in, const int* in_sizes, int n_in,
                              void* d_out, int out_size, void* d_ws, size_t ws_size,
                              hipStream_t stream) {
    (void)in_sizes; (void)n_in; (void)out_size; (void)ws_size;
    const int*   x     = (const int*)d_in[0];
    const float* embed = (const float*)d_in[1];
    const float* wg    = (const float*)d_in[2];
    const float* wi    = (const float*)d_in[3];
    const float* wf    = (const float*)d_in[4];
    const float* wo    = (const float*)d_in[5];
    const float* bg    = (const float*)d_in[6];
    const float* bi    = (const float*)d_in[7];
    const float* bff   = (const float*)d_in[8];
    const float* bo    = (const float*)d_in[9];
    const float* wp    = (const float*)d_in[10];
    const float* bp    = (const float*)d_in[11];
    float* out = (float*)d_out;

    char* ws = (char*)d_ws;
    float*          T  = (float*)(ws);                        // 2 MB  [128][4096]
    __hip_bfloat16* Wb = (__hip_bfloat16*)(ws + (2u << 20));  // 8 MB  [4096][1024]
    __hip_bfloat16* Bh = (__hip_bfloat16*)(ws + (10u << 20)); // 2 MB  [1024][1024]
    float*          A  = (float*)(ws + (12u << 20));          // 4 MB  [1024][1024]
    float*          Z  = (float*)(ws + (16u << 20));          // 16 MB [1024][4096]

    prep_table<<<16, 256, 0, stream>>>(embed, wg, wi, wf, wo, bg, bi, bff, bo, T);
    pack_w<<<4096, 256, 0, stream>>>(wg, wi, wf, wo, Wb);

    // t = 0: b_prev = 0, a_prev = 0 -> gates come from table only
    gates_step<<<1024, 256, 0, stream>>>(Z, T, x, A, Bh, 0, 1);
    for (int t = 1; t < 128; ++t) {
        dim3 grid(16, 32);
        gemm_step<<<grid, 256, 0, stream>>>(Bh, Wb, Z);
        gates_step<<<1024, 256, 0, stream>>>(Z, T, x, A, Bh, t, 0);
    }
    proj_softmax<<<1024, 256, 0, stream>>>(A, wp, bp, out);
}